// Round 1
// 491.630 us; speedup vs baseline: 1.0427x; 1.0427x over previous
//
#include <hip/hip_runtime.h>

// EntNet: B=32, S=256, L=64, D=100, M=20
// K1 encode_k : one row/block contiguous streaming -> LDS stage -> column reduce
// K0 prep_k   : T[d][e] = W[e][d] / keys
// K2 project_k: sWp = enc·W^T, kg = enc·keys^T via T
// K3 entnet_scan: 640 chains, 1 wave each. Matvec cand-broadcast via 512B LDS
//    round-trip (2 ds_write + 25 uniform ds_read_b128, single-wave in-order,
//    no barrier) + v_pk_fma_f32 packed accumulate: per-step VALU issue
//    ~370 -> ~210 instrs, no VALU->SGPR readlane hazards.

typedef float v2f __attribute__((ext_vector_type(2)));

__global__ __launch_bounds__(320) void encode_k(
    const float* __restrict__ batch,
    const float* __restrict__ encm,
    float* __restrict__ enc)
{
    __shared__ float prod[6400];
    __shared__ float part[200];
    const int t = threadIdx.x;
    const int row = blockIdx.x;       // 8192 blocks
    const float4* rb = (const float4*)batch + (size_t)row * 1600;
    const float4* e4 = (const float4*)encm;
    float4* p4 = (float4*)prod;
    #pragma unroll
    for (int i = 0; i < 5; ++i) {
        const int idx = i * 320 + t;
        float4 x = rb[idx];
        float4 mu = e4[idx];
        float4 p;
        p.x = x.x * mu.x; p.y = x.y * mu.y; p.z = x.z * mu.z; p.w = x.w * mu.w;
        p4[idx] = p;
    }
    __syncthreads();
    if (t < 200) {
        const int c = (t < 100) ? t : (t - 100);
        const int l0 = (t < 100) ? 0 : 32;
        float s0 = 0.f, s1 = 0.f;
        #pragma unroll
        for (int l = 0; l < 32; l += 2) {
            s0 += prod[(l0 + l) * 100 + c];
            s1 += prod[(l0 + l + 1) * 100 + c];
        }
        part[t] = s0 + s1;
    }
    __syncthreads();
    if (t < 100) enc[(size_t)row * 100 + t] = part[t] + part[100 + t];
}

__global__ void prep_k(const float* __restrict__ W,
                       const float* __restrict__ keys,
                       float* __restrict__ T)
{
    const int d = blockIdx.x;
    const int e = threadIdx.x;
    float v = 0.f;
    if (e < 100) v = W[e * 100 + d];
    else if (e < 120) v = keys[(e - 100) * 100 + d];
    T[d * 128 + e] = v;
}

__global__ __launch_bounds__(128) void project_k(
    const float* __restrict__ enc,
    const float* __restrict__ T,
    float* __restrict__ sWp,
    float* __restrict__ kg)
{
    __shared__ float encS[400];
    const int t = threadIdx.x;
    const int row0 = blockIdx.x * 4;
    if (t < 100) ((float4*)encS)[t] = ((const float4*)(enc + (size_t)row0 * 100))[t];
    __syncthreads();
    float a0 = 0.f, a1 = 0.f, a2 = 0.f, a3 = 0.f;
    #pragma unroll 4
    for (int d = 0; d < 100; ++d) {
        const float w = T[d * 128 + t];
        a0 += w * encS[d];
        a1 += w * encS[100 + d];
        a2 += w * encS[200 + d];
        a3 += w * encS[300 + d];
    }
    if (t < 100) {
        sWp[(size_t)row0 * 100 + t]       = a0;
        sWp[(size_t)(row0 + 1) * 100 + t] = a1;
        sWp[(size_t)(row0 + 2) * 100 + t] = a2;
        sWp[(size_t)(row0 + 3) * 100 + t] = a3;
    } else if (t < 120) {
        const int m = t - 100;
        kg[(size_t)row0 * 20 + m]       = a0;
        kg[(size_t)(row0 + 1) * 20 + m] = a1;
        kg[(size_t)(row0 + 2) * 20 + m] = a2;
        kg[(size_t)(row0 + 3) * 20 + m] = a3;
    }
}

template <int CTRL>
__device__ __forceinline__ float dpp_add_f(float x) {
    int s = __builtin_amdgcn_update_dpp(0, __float_as_int(x), CTRL, 0xF, 0xF, true);
    return x + __int_as_float(s);
}
__device__ __forceinline__ float lane63(float x) {
    return __int_as_float(__builtin_amdgcn_readlane(__float_as_int(x), 63));
}
#define DPP6(v) v = dpp_add_f<0x111>(v); v = dpp_add_f<0x112>(v); v = dpp_add_f<0x114>(v); \
                v = dpp_add_f<0x118>(v); v = dpp_add_f<0x142>(v); v = dpp_add_f<0x143>(v);

// Store cand to LDS: lane -> cbuf[lane] (k=0..63), cbuf[64+lane] (k=64..99;
// lanes 36..63 write the 100..127 pad, never read).
#define CAND_STORE(C0, C1) { cbuf[lane] = (C0); cbuf[64 + lane] = (C1); }

// RES(v2f) = U[e0/e1,:] . cand. 25 uniform ds_read_b128 broadcasts + 100
// v_pk_fma_f32 (natural (k,k+1) pairing: no splat, no op_sel needed).
#define MATVEC_READ(RES)                                                \
    {                                                                   \
        v2f A0 = {0.f, 0.f}, A1 = {0.f, 0.f};                           \
        v2f A2 = {0.f, 0.f}, A3 = {0.f, 0.f};                           \
        _Pragma("unroll")                                               \
        for (int j = 0; j < 25; ++j) {                                  \
            float4 cc = cbuf4[j];                                       \
            v2f clo = {cc.x, cc.y};                                     \
            v2f chi = {cc.z, cc.w};                                     \
            A0 = __builtin_elementwise_fma(UE0[2 * j],     clo, A0);    \
            A1 = __builtin_elementwise_fma(UE0[2 * j + 1], chi, A1);    \
            A2 = __builtin_elementwise_fma(UE1[2 * j],     clo, A2);    \
            A3 = __builtin_elementwise_fma(UE1[2 * j + 1], chi, A3);    \
        }                                                               \
        v2f sA = A0 + A1, sB = A2 + A3;                                 \
        RES.x = sA.x + sA.y;                                            \
        RES.y = sB.x + sB.y;                                            \
    }

__global__ __attribute__((amdgpu_waves_per_eu(1, 1))) __launch_bounds__(64)
void entnet_scan(
    const float* __restrict__ enc,    // [8192*100]
    const float* __restrict__ sWp,    // [8192*100]
    const float* __restrict__ kg,     // [8192*20]
    const float* __restrict__ keys,   // [20*100]
    const float* __restrict__ U,      // [100*100]
    const float* __restrict__ V,      // [100*100]
    const float* __restrict__ paPtr,
    float* __restrict__ out)          // [32*20*100]
{
    __shared__ float4 cbuf4[32];      // 128 floats: cand broadcast buffer
    float* cbuf = (float*)cbuf4;
    const int lane = threadIdx.x;
    // XCD swizzle: XCD = blockIdx%8 serves b in {4*xcd .. 4*xcd+3}
    const int xcd = blockIdx.x & 7;
    const int gg  = blockIdx.x >> 3;          // 0..79
    const int b = xcd * 4 + gg / 20;
    const int m = gg % 20;
    const bool hi = (lane < 36);
    const float h = hi ? 1.f : 0.f;
    const int e0 = lane;
    const int e1 = hi ? (64 + lane) : 99;
    const float pa = paPtr[0];

    // U rows e0/e1 as (k,k+1) v2f pairs: UE0[j] = {U[e0][2j], U[e0][2j+1]}
    v2f UE0[50], UE1[50];
    {
        const float4* u0 = (const float4*)(U + e0 * 100);
        const float4* u1 = (const float4*)(U + e1 * 100);
        #pragma unroll
        for (int k = 0; k < 25; ++k) {
            float4 a = u0[k], c = u1[k];
            UE0[2 * k]     = (v2f){a.x, a.y};
            UE0[2 * k + 1] = (v2f){a.z, a.w};
            UE1[2 * k]     = (v2f){c.x, c.y};
            UE1[2 * k + 1] = (v2f){c.z, c.w};
        }
    }

    float kv0 = 0.f, kv1 = 0.f;
    {
        const float4* km = (const float4*)(keys + m * 100);
        const float4* v0 = (const float4*)(V + e0 * 100);
        const float4* v1 = (const float4*)(V + e1 * 100);
        #pragma unroll
        for (int k = 0; k < 25; ++k) {
            float4 kk = km[k], a = v0[k], c = v1[k];
            kv0 += a.x * kk.x + a.y * kk.y + a.z * kk.z + a.w * kk.w;
            kv1 += c.x * kk.x + c.y * kk.y + c.z * kk.z + c.w * kk.w;
        }
    }
    const float k0 = keys[m * 100 + e0];
    const float k1 = h * keys[m * 100 + e1];
    float nm0 = k0, nm1 = k1;        // unnormalized mem; true mem = rn*nm

    v2f P;                            // P = U . nm (register recurrence)
    CAND_STORE(k0, k1);
    MATVEC_READ(P);

    float nq = k0 * k0 + k1 * k1;     // ||mem_0||^2
    DPP6(nq)
    float nsq = lane63(nq);
    float rn = 1.f;

    const float* encRow = enc + (size_t)b * 25600;
    const float* sWRow  = sWp + (size_t)b * 25600;
    const float* kgRow  = kg + (size_t)b * 5120 + m;

    float sw0 = sWRow[e0], sw1 = sWRow[e1];
    float g;
    {
        const float sv0 = encRow[e0], sv1 = encRow[e1];
        const float kg0 = kgRow[0];
        float q1 = sv0 * nm0 + sv1 * nm1;
        DPP6(q1)
        const float Q1 = lane63(q1);
        g = 1.f / (1.f + __expf(-(Q1 + kg0)));   // rn == 1 at t=0
    }

    for (int step = 0; step < 256; ++step) {
        const int nxt = (step < 255 ? step + 1 : 255);
        const float nsv0 = encRow[nxt * 100 + e0], nsv1 = encRow[nxt * 100 + e1];
        const float nsw0 = sWRow[nxt * 100 + e0], nsw1 = sWRow[nxt * 100 + e1];
        const float nkg  = kgRow[nxt * 20];

        // critical path: P -> x -> cand -> LDS round-trip matvec -> P'
        const float x0 = rn * P.x + kv0 + sw0;
        const float x1 = rn * P.y + kv1 + sw1;
        float c0 = (x0 >= 0.f) ? x0 : pa * x0;
        float c1 = (x1 >= 0.f) ? x1 : pa * x1;
        c1 *= h;

        CAND_STORE(c0, c1);           // issue early: LDS latency hides under DPP

        // off-path norm partials (overlap LDS round-trip)
        float q3 = nm0 * c0 + nm1 * c1;             // nm . cand
        float p4 = c0 * c0 + c1 * c1;               // cand . cand
        #define RND2(C) q3 = dpp_add_f<C>(q3); p4 = dpp_add_f<C>(p4);
        RND2(0x111) RND2(0x112) RND2(0x114) RND2(0x118) RND2(0x142) RND2(0x143)
        #undef RND2

        v2f Q;
        MATVEC_READ(Q);

        const float Q3 = lane63(q3);
        const float P4 = lane63(p4);
        const float n2 = nsq + 2.f * (g * rn) * Q3 + g * g * P4;
        const float rnn = rsqrtf(n2);               // rn_{t+1}
        nsq = 1.f;

        nm0 = rn * nm0 + g * c0;
        nm1 = rn * nm1 + g * c1;
        P.x = rn * P.x + g * Q.x;
        P.y = rn * P.y + g * Q.y;

        // gate for step t+1 (overlaps next iteration's front)
        float q1 = nsv0 * nm0 + nsv1 * nm1;
        DPP6(q1)
        const float Q1 = lane63(q1);
        g = 1.f / (1.f + __expf(-(rnn * Q1 + nkg)));

        rn = rnn;
        sw0 = nsw0; sw1 = nsw1;
    }
    float* orow = out + (size_t)(b * 20 + m) * 100;
    orow[e0] = nm0 * rn;
    if (hi) orow[e1] = nm1 * rn;
}

extern "C" void kernel_launch(void* const* d_in, const int* in_sizes, int n_in,
                              void* d_out, int out_size, void* d_ws, size_t ws_size,
                              hipStream_t stream) {
    const float* batch = (const float*)d_in[0];
    const float* encm  = (const float*)d_in[1];
    const float* keys  = (const float*)d_in[2];
    const float* U     = (const float*)d_in[3];
    const float* V     = (const float*)d_in[4];
    const float* W     = (const float*)d_in[5];
    const float* pa    = (const float*)d_in[6];
    float* out = (float*)d_out;

    float* enc = (float*)d_ws;          // 819200 floats
    float* sWp = enc + 819200;          // 819200 floats
    float* kgb = sWp + 819200;          // 163840 floats
    float* T   = kgb + 163840;          // 12800 floats

    encode_k<<<8192, 320, 0, stream>>>(batch, encm, enc);
    prep_k<<<100, 128, 0, stream>>>(W, keys, T);
    project_k<<<2048, 128, 0, stream>>>(enc, T, sWp, kgb);
    entnet_scan<<<640, 64, 0, stream>>>(enc, sWp, kgb, keys, U, V, pa, out);
}